// Round 12
// baseline (744.436 us; speedup 1.0000x reference)
//
#include <hip/hip_runtime.h>
#include <hip/hip_bf16.h>

#define SEQ   20
#define PRED  30
#define TSTEPS (SEQ + PRED)
#define PEDS  16384
#define EMB   64
#define RNN   128
#define KTOT  192
#define PB    64
#define NT    1024

typedef _Float16 half8 __attribute__((ext_vector_type(8)));
typedef _Float16 half4 __attribute__((ext_vector_type(4)));
typedef __attribute__((ext_vector_type(4))) float f32x4;

__device__ __forceinline__ float sigm(float x) {
    return 1.f / (1.f + __expf(-x));
}
__device__ __forceinline__ float tanhfast(float x) {
    x = fmaxf(x, -15.f);
    float e = __expf(-2.f * x);
    return (1.f - e) / (1.f + e);
}

// B fragments (f16) pre-permuted: idx = ((kt*32 + nt)*64 + l)*8 + i ; nt = g*8 + jt
// row n = g*128 + jt*16 + (l&15) ; k = kt*32 + (l>>4)*8 + i
// W_cat[n][k]: k<64 -> W_ih[n][k], else W_hh[n][k-64].
// ewp[ke][4] = {Wemb[ke][0], Wemb[ke][1], bemb[ke], 0}
__global__ void prep_kernel(const float* __restrict__ Wih, const float* __restrict__ Whh,
                            const float* __restrict__ Wemb, const float* __restrict__ bemb,
                            _Float16* __restrict__ Bp, float* __restrict__ ewp) {
    int t = blockIdx.x * blockDim.x + threadIdx.x;
    if (t < 64) {
        ewp[t * 4 + 0] = Wemb[t * 2 + 0];
        ewp[t * 4 + 1] = Wemb[t * 2 + 1];
        ewp[t * 4 + 2] = bemb[t];
        ewp[t * 4 + 3] = 0.f;
    }
    if (t >= 6 * 32 * 64 * 8) return;
    int i  = t & 7;
    int l  = (t >> 3) & 63;
    int nt = (t >> 9) & 31;
    int kt = t >> 14;
    int n = (nt >> 3) * RNN + (nt & 7) * 16 + (l & 15);
    int k = kt * 32 + ((l >> 4) << 3) + i;
    float val = (k < EMB) ? Wih[n * EMB + k] : Whh[n * RNN + (k - EMB)];
    Bp[t] = (_Float16)val;
}

// One 1024-thread block per CU: 16 waves = 4 waves/SIMD within one barrier
// domain. CORRECTNESS INVARIANT (learned R11): every wave must itself stage
// (global_load_lds) every B fragment it reads, because per-wave vmcnt is the
// only thing ordering stage->read. Waves sharing a jt duplicate-load the same
// fragments to the same LDS address (identical bytes -> benign).
__global__ __launch_bounds__(NT) void lstm_kernel(
    const float* __restrict__ obs,
    const float* __restrict__ ewp,
    const float* __restrict__ bih,  const float* __restrict__ bhh,
    const _Float16* __restrict__ Bp,
    const float* __restrict__ Wout, const float* __restrict__ bout,
    float* __restrict__ out)
{
    // A = [e(64) ; h(128)] single-plane f16, row-major [64 ped][192 k] (384 B rows),
    // XOR-swizzled. B staged per-kt (32 KB slices) double-buffered.
    __shared__ __align__(16) char smA[64 * 384];    // 24 KB
    __shared__ __align__(16) char smB[2 * 32768];   // 64 KB B dbuf
    __shared__ float part[64 * 2 * 8];              // 4 KB
    __shared__ float outs[64 * 2];

    const int tid = threadIdx.x;
    const int l   = tid & 63;
    const int w   = __builtin_amdgcn_readfirstlane(tid >> 6);  // wave 0..15
    const int jt  = w >> 1;   // j-tile 0..7
    const int mth = w & 1;    // ped-half

    // zero A (h region must be 0 at step 0)
    for (int r = tid; r < (64 * 384) / 4; r += NT) ((int*)smA)[r] = 0;

    const int jlane = jt * 16 + (l & 15);  // this lane's j column
    const int lrow  = (l >> 4) << 2;       // C/D row base
    const int kgrp  = (l >> 4) << 3;       // A/B k-group base

    float bias[4];
#pragma unroll
    for (int g = 0; g < 4; ++g) {
        int n = g * RNN + jlane;
        bias[g] = bih[n] + bhh[n];
    }

    // E-phase mapping: thread = (ped = tid&63, kq = tid>>6); 4 k's per thread.
    const int eped = tid & 63;
    const int ekq  = tid >> 6;  // 0..15
    const int epg  = blockIdx.x * PB + eped;
    f32x4 ew[4];
#pragma unroll
    for (int q = 0; q < 4; ++q)
        ew[q] = *(const f32x4*)(ewp + (ekq * 4 + q) * 4);

    float c[8];
#pragma unroll
    for (int q = 0; q < 8; ++q) c[q] = 0.f;

    // stage B slice kt into buffer buf: wave stages ALL 4 fragments it reads
    // (nt = g*8 + jt), 1 KB each; LDS dst = uniform base + lane*16 (linear).
    auto stage = [&](int kt, int buf) {
#pragma unroll
        for (int g = 0; g < 4; ++g) {
            int nt = g * 8 + jt;
            const _Float16* src = Bp + (((size_t)kt * 32 + nt) * 64 + l) * 8;
            __builtin_amdgcn_global_load_lds(
                (const __attribute__((address_space(1))) void*)src,
                (__attribute__((address_space(3))) void*)(smB + buf * 32768 + nt * 1024),
                16, 0, 0);
        }
    };

    stage(0, 0);  // prologue: kt0 -> buf0
    __syncthreads();

    for (int step = 0; step < TSTEPS; ++step) {
        // ---- E: e = relu(x @ Wemb.T + bemb) -> A rows k=0..63 (f16)
        {
            float x0, x1;
            if (step < SEQ) {
                const float* xp = obs + ((size_t)step * PEDS + epg) * 2;
                x0 = xp[0]; x1 = xp[1];
            } else {
                x0 = outs[eped * 2 + 0];
                x1 = outs[eped * 2 + 1];
            }
            half4 vh;
#pragma unroll
            for (int q = 0; q < 4; ++q) {
                float v = fmaf(x0, ew[q][0], fmaf(x1, ew[q][1], ew[q][2]));
                v = v > 0.f ? v : 0.f;
                vh[q] = (_Float16)v;
            }
            int off = (eped * 384 + ekq * 8) ^ ((eped & 7) << 4);
            *(half4*)(smA + off) = vh;
        }
        __syncthreads();  // B1: e (this step) + h (prev step) visible

        // ---- G: gates = A[64x192] @ B[192x512] + bias ; f16 1-pass, 6 kt phases
        f32x4 acc[2][4];  // [mt][gate]
#pragma unroll
        for (int mt = 0; mt < 2; ++mt)
#pragma unroll
            for (int g = 0; g < 4; ++g) {
                acc[mt][g][0] = bias[g]; acc[mt][g][1] = bias[g];
                acc[mt][g][2] = bias[g]; acc[mt][g][3] = bias[g];
            }
#pragma unroll
        for (int kt = 0; kt < 6; ++kt) {
            const int buf  = kt & 1;
            const int ktn  = (kt < 5) ? kt + 1 : 0;  // kt=5 prefetches next step's kt0
            const int bufn = buf ^ 1;
            stage(ktn, bufn);
            // this wave's current-buf 4 loads are oldest; allow the 4 just issued
            asm volatile("s_waitcnt vmcnt(4)" ::: "memory");
            half8 bf[4];
#pragma unroll
            for (int g = 0; g < 4; ++g)
                bf[g] = *((const half8*)(smB + buf * 32768 + (g * 8 + jt) * 1024) + l);
#pragma unroll
            for (int mt = 0; mt < 2; ++mt) {
                int ped = mth * 32 + mt * 16 + (l & 15);
                int off = (ped * 384 + (kt * 32 + kgrp) * 2) ^ ((ped & 7) << 4);
                half8 ah = *(const half8*)(smA + off);
#pragma unroll
                for (int g = 0; g < 4; ++g)
                    acc[mt][g] = __builtin_amdgcn_mfma_f32_16x16x32_f16(ah, bf[g], acc[mt][g], 0, 0, 0);
            }
        }
        __syncthreads();  // B2: all A reads done before h overwrite

        // ---- S: nonlinearities + c/h update; lane owns (ped, j = jlane)
#pragma unroll
        for (int mt = 0; mt < 2; ++mt) {
#pragma unroll
            for (int r = 0; r < 4; ++r) {
                float gi = acc[mt][0][r], gf = acc[mt][1][r];
                float gg = acc[mt][2][r], go = acc[mt][3][r];
                float i_ = sigm(gi), f_ = sigm(gf), g_ = tanhfast(gg), o_ = sigm(go);
                float cn = fmaf(f_, c[mt * 4 + r], i_ * g_);
                c[mt * 4 + r] = cn;
                float hn = o_ * tanhfast(cn);
                int ped = mth * 32 + mt * 16 + lrow + r;
                int offb = (ped * 384 + 128 + jlane * 2) ^ ((ped & 7) << 4);
                *(_Float16*)(smA + offb) = (_Float16)hn;
            }
        }

        // ---- O: out = h @ Wout.T + bout (h f16 from LDS); 16 waves, 16-j slices
        if (step >= SEQ - 1) {
            __syncthreads();  // B3: h(step) visible
            {
                const int oo = w & 1, jq = w >> 1;  // jq 0..7
                float s = 0.f;
#pragma unroll
                for (int t = 0; t < 2; ++t) {
                    int j = jq * 16 + t * 8;
                    int off = (l * 384 + 128 + j * 2) ^ ((l & 7) << 4);
                    half8 hh8 = *(const half8*)(smA + off);
                    const f32x4 w0 = *(const f32x4*)(Wout + oo * RNN + j);
                    const f32x4 w1 = *(const f32x4*)(Wout + oo * RNN + j + 4);
#pragma unroll
                    for (int i = 0; i < 4; ++i) {
                        s = fmaf((float)hh8[i], w0[i], s);
                        s = fmaf((float)hh8[i + 4], w1[i], s);
                    }
                }
                part[(l * 2 + oo) * 8 + jq] = s;
            }
            __syncthreads();  // B4
            if (tid < 128) {
                int pp = tid & 63, o2 = tid >> 6;
                const float* pr = &part[(pp * 2 + o2) * 8];
                float o = bout[o2] + (((pr[0] + pr[1]) + (pr[2] + pr[3])) +
                                      ((pr[4] + pr[5]) + (pr[6] + pr[7])));
                outs[pp * 2 + o2] = o;
                if (step >= SEQ)
                    out[((size_t)(step - SEQ) * PEDS + (blockIdx.x * PB + pp)) * 2 + o2] = o;
            }
            __syncthreads();  // B5: outs visible for next E
        }
    }
}

extern "C" void kernel_launch(void* const* d_in, const int* in_sizes, int n_in,
                              void* d_out, int out_size, void* d_ws, size_t ws_size,
                              hipStream_t stream) {
    const float* obs  = (const float*)d_in[0];
    const float* Wemb = (const float*)d_in[1];
    const float* bemb = (const float*)d_in[2];
    const float* Wih  = (const float*)d_in[3];
    const float* bih  = (const float*)d_in[4];
    const float* Whh  = (const float*)d_in[5];
    const float* bhh  = (const float*)d_in[6];
    const float* Wout = (const float*)d_in[7];
    const float* bout = (const float*)d_in[8];

    _Float16* Bp  = (_Float16*)d_ws;                 // 98304 f16 = 192 KB
    float*    ewp = (float*)(Bp + 6 * 32 * 64 * 8);  // 64*4 f32 = 1 KB

    prep_kernel<<<(6 * 32 * 64 * 8 + 255) / 256, 256, 0, stream>>>(Wih, Whh, Wemb, bemb, Bp, ewp);
    lstm_kernel<<<PEDS / PB, NT, 0, stream>>>(obs, ewp, bih, bhh, Bp, Wout, bout, (float*)d_out);
}

// Round 13
// 743.543 us; speedup vs baseline: 1.0012x; 1.0012x over previous
//
#include <hip/hip_runtime.h>
#include <hip/hip_bf16.h>

#define SEQ   20
#define PRED  30
#define TSTEPS (SEQ + PRED)
#define PEDS  16384
#define EMB   64
#define RNN   128
#define KTOT  192
#define PB    64
#define NT    1024

typedef _Float16 half8 __attribute__((ext_vector_type(8)));
typedef _Float16 half4 __attribute__((ext_vector_type(4)));
typedef __attribute__((ext_vector_type(4))) float f32x4;

__device__ __forceinline__ float sigm(float x) {
    return 1.f / (1.f + __expf(-x));
}
__device__ __forceinline__ float tanhfast(float x) {
    x = fmaxf(x, -15.f);
    float e = __expf(-2.f * x);
    return (1.f - e) / (1.f + e);
}

// B fragments (f16) pre-permuted: idx = ((kt*32 + nt)*64 + l)*8 + i ; nt = g*8 + jt
// row n = g*128 + jt*16 + (l&15) ; k = kt*32 + (l>>4)*8 + i
// W_cat[n][k]: k<64 -> W_ih[n][k], else W_hh[n][k-64].
// ewp[ke][4] = {Wemb[ke][0], Wemb[ke][1], bemb[ke], 0}
__global__ void prep_kernel(const float* __restrict__ Wih, const float* __restrict__ Whh,
                            const float* __restrict__ Wemb, const float* __restrict__ bemb,
                            _Float16* __restrict__ Bp, float* __restrict__ ewp) {
    int t = blockIdx.x * blockDim.x + threadIdx.x;
    if (t < 64) {
        ewp[t * 4 + 0] = Wemb[t * 2 + 0];
        ewp[t * 4 + 1] = Wemb[t * 2 + 1];
        ewp[t * 4 + 2] = bemb[t];
        ewp[t * 4 + 3] = 0.f;
    }
    if (t >= 6 * 32 * 64 * 8) return;
    int i  = t & 7;
    int l  = (t >> 3) & 63;
    int nt = (t >> 9) & 31;
    int kt = t >> 14;
    int n = (nt >> 3) * RNN + (nt & 7) * 16 + (l & 15);
    int k = kt * 32 + ((l >> 4) << 3) + i;
    float val = (k < EMB) ? Wih[n * EMB + k] : Whh[n * RNN + (k - EMB)];
    Bp[t] = (_Float16)val;
}

// 16 waves/block, 1 block/CU = 4 waves/SIMD. launch_bounds(1024,1): promise
// only 1 wave/EU so the allocator gives the ~110 VGPRs the code needs (<=128
// keeps 16 waves/CU resident). VGPR-cap ledger: (512,2)->128 ok, (512,4)->64
// spill, (1024,4)->64 spill, (1024,default)->64 spill.
// CORRECTNESS INVARIANT (R11): every wave itself stages (global_load_lds)
// every B fragment it reads; per-wave vmcnt is the only stage->read ordering.
__global__ __launch_bounds__(NT, 1) void lstm_kernel(
    const float* __restrict__ obs,
    const float* __restrict__ ewp,
    const float* __restrict__ bih,  const float* __restrict__ bhh,
    const _Float16* __restrict__ Bp,
    const float* __restrict__ Wout, const float* __restrict__ bout,
    float* __restrict__ out)
{
    // A = [e(64) ; h(128)] single-plane f16, row-major [64 ped][192 k] (384 B rows),
    // XOR-swizzled. B staged per-kt (32 KB slices) double-buffered.
    __shared__ __align__(16) char smA[64 * 384];    // 24 KB
    __shared__ __align__(16) char smB[2 * 32768];   // 64 KB B dbuf
    __shared__ float part[64 * 2 * 8];              // 4 KB
    __shared__ float outs[64 * 2];

    const int tid = threadIdx.x;
    const int l   = tid & 63;
    const int w   = __builtin_amdgcn_readfirstlane(tid >> 6);  // wave 0..15
    const int jt  = w >> 1;   // j-tile 0..7
    const int mth = w & 1;    // ped-half

    // zero A (h region must be 0 at step 0)
    for (int r = tid; r < (64 * 384) / 4; r += NT) ((int*)smA)[r] = 0;

    const int jlane = jt * 16 + (l & 15);  // this lane's j column
    const int lrow  = (l >> 4) << 2;       // C/D row base
    const int kgrp  = (l >> 4) << 3;       // A/B k-group base

    float bias[4];
#pragma unroll
    for (int g = 0; g < 4; ++g) {
        int n = g * RNN + jlane;
        bias[g] = bih[n] + bhh[n];
    }

    // E-phase mapping: thread = (ped = tid&63, kq = tid>>6); 4 k's per thread.
    const int eped = tid & 63;
    const int ekq  = tid >> 6;  // 0..15
    const int epg  = blockIdx.x * PB + eped;
    f32x4 ew[4];
#pragma unroll
    for (int q = 0; q < 4; ++q)
        ew[q] = *(const f32x4*)(ewp + (ekq * 4 + q) * 4);

    float c[8];
#pragma unroll
    for (int q = 0; q < 8; ++q) c[q] = 0.f;

    // stage B slice kt into buffer buf: wave stages ALL 4 fragments it reads
    // (nt = g*8 + jt), 1 KB each; LDS dst = uniform base + lane*16 (linear).
    auto stage = [&](int kt, int buf) {
#pragma unroll
        for (int g = 0; g < 4; ++g) {
            int nt = g * 8 + jt;
            const _Float16* src = Bp + (((size_t)kt * 32 + nt) * 64 + l) * 8;
            __builtin_amdgcn_global_load_lds(
                (const __attribute__((address_space(1))) void*)src,
                (__attribute__((address_space(3))) void*)(smB + buf * 32768 + nt * 1024),
                16, 0, 0);
        }
    };

    stage(0, 0);  // prologue: kt0 -> buf0
    __syncthreads();

    for (int step = 0; step < TSTEPS; ++step) {
        // ---- E: e = relu(x @ Wemb.T + bemb) -> A rows k=0..63 (f16)
        {
            float x0, x1;
            if (step < SEQ) {
                const float* xp = obs + ((size_t)step * PEDS + epg) * 2;
                x0 = xp[0]; x1 = xp[1];
            } else {
                x0 = outs[eped * 2 + 0];
                x1 = outs[eped * 2 + 1];
            }
            half4 vh;
#pragma unroll
            for (int q = 0; q < 4; ++q) {
                float v = fmaf(x0, ew[q][0], fmaf(x1, ew[q][1], ew[q][2]));
                v = v > 0.f ? v : 0.f;
                vh[q] = (_Float16)v;
            }
            int off = (eped * 384 + ekq * 8) ^ ((eped & 7) << 4);
            *(half4*)(smA + off) = vh;
        }
        __syncthreads();  // B1: e (this step) + h (prev step) visible

        // ---- G: gates = A[64x192] @ B[192x512] + bias ; f16 1-pass, 6 kt phases
        f32x4 acc[2][4];  // [mt][gate]
#pragma unroll
        for (int mt = 0; mt < 2; ++mt)
#pragma unroll
            for (int g = 0; g < 4; ++g) {
                acc[mt][g][0] = bias[g]; acc[mt][g][1] = bias[g];
                acc[mt][g][2] = bias[g]; acc[mt][g][3] = bias[g];
            }
#pragma unroll
        for (int kt = 0; kt < 6; ++kt) {
            const int buf  = kt & 1;
            const int ktn  = (kt < 5) ? kt + 1 : 0;  // kt=5 prefetches next step's kt0
            const int bufn = buf ^ 1;
            stage(ktn, bufn);
            // this wave's current-buf 4 loads are oldest; allow the 4 just issued
            asm volatile("s_waitcnt vmcnt(4)" ::: "memory");
            half8 bf[4];
#pragma unroll
            for (int g = 0; g < 4; ++g)
                bf[g] = *((const half8*)(smB + buf * 32768 + (g * 8 + jt) * 1024) + l);
#pragma unroll
            for (int mt = 0; mt < 2; ++mt) {
                int ped = mth * 32 + mt * 16 + (l & 15);
                int off = (ped * 384 + (kt * 32 + kgrp) * 2) ^ ((ped & 7) << 4);
                half8 ah = *(const half8*)(smA + off);
#pragma unroll
                for (int g = 0; g < 4; ++g)
                    acc[mt][g] = __builtin_amdgcn_mfma_f32_16x16x32_f16(ah, bf[g], acc[mt][g], 0, 0, 0);
            }
        }
        __syncthreads();  // B2: all A reads done before h overwrite

        // ---- S: nonlinearities + c/h update; lane owns (ped, j = jlane)
#pragma unroll
        for (int mt = 0; mt < 2; ++mt) {
#pragma unroll
            for (int r = 0; r < 4; ++r) {
                float gi = acc[mt][0][r], gf = acc[mt][1][r];
                float gg = acc[mt][2][r], go = acc[mt][3][r];
                float i_ = sigm(gi), f_ = sigm(gf), g_ = tanhfast(gg), o_ = sigm(go);
                float cn = fmaf(f_, c[mt * 4 + r], i_ * g_);
                c[mt * 4 + r] = cn;
                float hn = o_ * tanhfast(cn);
                int ped = mth * 32 + mt * 16 + lrow + r;
                int offb = (ped * 384 + 128 + jlane * 2) ^ ((ped & 7) << 4);
                *(_Float16*)(smA + offb) = (_Float16)hn;
            }
        }

        // ---- O: out = h @ Wout.T + bout (h f16 from LDS); 16 waves, 16-j slices
        if (step >= SEQ - 1) {
            __syncthreads();  // B3: h(step) visible
            {
                const int oo = w & 1, jq = w >> 1;  // jq 0..7
                float s = 0.f;
#pragma unroll
                for (int t = 0; t < 2; ++t) {
                    int j = jq * 16 + t * 8;
                    int off = (l * 384 + 128 + j * 2) ^ ((l & 7) << 4);
                    half8 hh8 = *(const half8*)(smA + off);
                    const f32x4 w0 = *(const f32x4*)(Wout + oo * RNN + j);
                    const f32x4 w1 = *(const f32x4*)(Wout + oo * RNN + j + 4);
#pragma unroll
                    for (int i = 0; i < 4; ++i) {
                        s = fmaf((float)hh8[i], w0[i], s);
                        s = fmaf((float)hh8[i + 4], w1[i], s);
                    }
                }
                part[(l * 2 + oo) * 8 + jq] = s;
            }
            __syncthreads();  // B4
            if (tid < 128) {
                int pp = tid & 63, o2 = tid >> 6;
                const float* pr = &part[(pp * 2 + o2) * 8];
                float o = bout[o2] + (((pr[0] + pr[1]) + (pr[2] + pr[3])) +
                                      ((pr[4] + pr[5]) + (pr[6] + pr[7])));
                outs[pp * 2 + o2] = o;
                if (step >= SEQ)
                    out[((size_t)(step - SEQ) * PEDS + (blockIdx.x * PB + pp)) * 2 + o2] = o;
            }
            __syncthreads();  // B5: outs visible for next E
        }
    }
}

extern "C" void kernel_launch(void* const* d_in, const int* in_sizes, int n_in,
                              void* d_out, int out_size, void* d_ws, size_t ws_size,
                              hipStream_t stream) {
    const float* obs  = (const float*)d_in[0];
    const float* Wemb = (const float*)d_in[1];
    const float* bemb = (const float*)d_in[2];
    const float* Wih  = (const float*)d_in[3];
    const float* bih  = (const float*)d_in[4];
    const float* Whh  = (const float*)d_in[5];
    const float* bhh  = (const float*)d_in[6];
    const float* Wout = (const float*)d_in[7];
    const float* bout = (const float*)d_in[8];

    _Float16* Bp  = (_Float16*)d_ws;                 // 98304 f16 = 192 KB
    float*    ewp = (float*)(Bp + 6 * 32 * 64 * 8);  // 64*4 f32 = 1 KB

    prep_kernel<<<(6 * 32 * 64 * 8 + 255) / 256, 256, 0, stream>>>(Wih, Whh, Wemb, bemb, Bp, ewp);
    lstm_kernel<<<PEDS / PB, NT, 0, stream>>>(obs, ewp, bih, bhh, Bp, Wout, bout, (float*)d_out);
}

// Round 14
// 453.332 us; speedup vs baseline: 1.6421x; 1.6402x over previous
//
#include <hip/hip_runtime.h>
#include <hip/hip_bf16.h>

#define SEQ   20
#define PRED  30
#define TSTEPS (SEQ + PRED)
#define PEDS  16384
#define EMB   64
#define RNN   128
#define KTOT  192
#define PB    32
#define NT    512

typedef _Float16 half8 __attribute__((ext_vector_type(8)));
typedef _Float16 half4 __attribute__((ext_vector_type(4)));
typedef __attribute__((ext_vector_type(4))) float f32x4;

__device__ __forceinline__ float sigm(float x) {
    return 1.f / (1.f + __expf(-x));
}
__device__ __forceinline__ float tanhfast(float x) {
    x = fmaxf(x, -15.f);
    float e = __expf(-2.f * x);
    return (1.f - e) / (1.f + e);
}

// B fragments (f16) pre-permuted: idx = ((kt*32 + nt)*64 + l)*8 + i ; nt = g*8 + jt
// row n = g*128 + jt*16 + (l&15) ; k = kt*32 + (l>>4)*8 + i
// W_cat[n][k]: k<64 -> W_ih[n][k], else W_hh[n][k-64].
// ewp[ke][4] = {Wemb[ke][0], Wemb[ke][1], bemb[ke], 0}
__global__ void prep_kernel(const float* __restrict__ Wih, const float* __restrict__ Whh,
                            const float* __restrict__ Wemb, const float* __restrict__ bemb,
                            _Float16* __restrict__ Bp, float* __restrict__ ewp) {
    int t = blockIdx.x * blockDim.x + threadIdx.x;
    if (t < 64) {
        ewp[t * 4 + 0] = Wemb[t * 2 + 0];
        ewp[t * 4 + 1] = Wemb[t * 2 + 1];
        ewp[t * 4 + 2] = bemb[t];
        ewp[t * 4 + 3] = 0.f;
    }
    if (t >= 6 * 32 * 64 * 8) return;
    int i  = t & 7;
    int l  = (t >> 3) & 63;
    int nt = (t >> 9) & 31;
    int kt = t >> 14;
    int n = (nt >> 3) * RNN + (nt & 7) * 16 + (l & 15);
    int k = kt * 32 + ((l >> 4) << 3) + i;
    float val = (k < EMB) ? Wih[n * EMB + k] : Whh[n * RNN + (k - EMB)];
    Bp[t] = (_Float16)val;
}

// PB=32, grid=512 -> 2 blocks/CU (pigeonhole). LDS ~46.4 KB/block so two
// blocks need only 93 KB of the 160 KB LDS: co-residency unambiguous.
// Two independent barrier domains per CU -> phase overlap across blocks.
// launch_bounds(512,2) -> 128 VGPR cap (ledger-proven); live set ~96 (R10).
// CORRECTNESS INVARIANT (R11): every wave itself stages (global_load_lds)
// every B fragment it reads; per-wave vmcnt is the only stage->read ordering.
__global__ __launch_bounds__(NT, 2) void lstm_kernel(
    const float* __restrict__ obs,
    const float* __restrict__ ewp,
    const float* __restrict__ bih,  const float* __restrict__ bhh,
    const _Float16* __restrict__ Bp,
    const float* __restrict__ Wout, const float* __restrict__ bout,
    float* __restrict__ out)
{
    // A = [e(64) ; h(128)] single-plane f16, row-major [32 ped][192 k] (384 B rows),
    // XOR-swizzled. B staged per HALF-kt (16 KB slices) double-buffered.
    __shared__ __align__(16) char smA[PB * 384];    // 12 KB
    __shared__ __align__(16) char smB[2 * 16384];   // 32 KB B dbuf
    __shared__ float part[PB * 2 * 4];              // 1 KB
    __shared__ float outs[PB * 2];

    const int tid = threadIdx.x;
    const int l   = tid & 63;
    const int w   = __builtin_amdgcn_readfirstlane(tid >> 6);  // wave 0..7 (= jt)

    // zero A (h region must be 0 at step 0)
    for (int r = tid; r < (PB * 384) / 4; r += NT) ((int*)smA)[r] = 0;

    const int jlane = w * 16 + (l & 15);  // this lane's j column
    const int lrow  = (l >> 4) << 2;      // C/D row base
    const int kgrp  = (l >> 4) << 3;      // A/B k-group base

    float bias[4];
#pragma unroll
    for (int g = 0; g < 4; ++g) {
        int n = g * RNN + jlane;
        bias[g] = bih[n] + bhh[n];
    }

    // E-phase mapping: thread = (ped = tid&31, kq = tid>>5); 4 k's per thread.
    const int eped = tid & 31;
    const int ekq  = tid >> 5;  // 0..15
    const int epg  = blockIdx.x * PB + eped;
    f32x4 ew[4];
#pragma unroll
    for (int q = 0; q < 4; ++q)
        ew[q] = *(const f32x4*)(ewp + (ekq * 4 + q) * 4);

    float c[8];
#pragma unroll
    for (int q = 0; q < 8; ++q) c[q] = 0.f;

    // stage phase ph (= kt*2 + hh): wave w stages the 2 fragments it will read
    // (nt = hh*16 + q*8 + w -> slot q*8+w), 1 KB each; LDS dst linear.
    auto stage = [&](int ph, int buf) {
        const int kt = ph >> 1, hh = ph & 1;
#pragma unroll
        for (int q = 0; q < 2; ++q) {
            int nt   = hh * 16 + q * 8 + w;
            int slot = q * 8 + w;
            const _Float16* src = Bp + (((size_t)kt * 32 + nt) * 64 + l) * 8;
            __builtin_amdgcn_global_load_lds(
                (const __attribute__((address_space(1))) void*)src,
                (__attribute__((address_space(3))) void*)(smB + buf * 16384 + slot * 1024),
                16, 0, 0);
        }
    };

    stage(0, 0);  // prologue: phase0 -> buf0
    __syncthreads();

    for (int step = 0; step < TSTEPS; ++step) {
        // ---- E: e = relu(x @ Wemb.T + bemb) -> A rows k=0..63 (f16)
        {
            float x0, x1;
            if (step < SEQ) {
                const float* xp = obs + ((size_t)step * PEDS + epg) * 2;
                x0 = xp[0]; x1 = xp[1];
            } else {
                x0 = outs[eped * 2 + 0];
                x1 = outs[eped * 2 + 1];
            }
            half4 vh;
#pragma unroll
            for (int q = 0; q < 4; ++q) {
                float v = fmaf(x0, ew[q][0], fmaf(x1, ew[q][1], ew[q][2]));
                v = v > 0.f ? v : 0.f;
                vh[q] = (_Float16)v;
            }
            int off = (eped * 384 + ekq * 8) ^ ((eped & 7) << 4);
            *(half4*)(smA + off) = vh;
        }
        __syncthreads();  // B1: e (this step) + h (prev step) visible

        // ---- G: gates = A[32x192] @ B[192x512] + bias ; f16 1-pass, 12 phases
        f32x4 acc[2][4];  // [mt][gate]
#pragma unroll
        for (int mt = 0; mt < 2; ++mt)
#pragma unroll
            for (int g = 0; g < 4; ++g) {
                acc[mt][g][0] = bias[g]; acc[mt][g][1] = bias[g];
                acc[mt][g][2] = bias[g]; acc[mt][g][3] = bias[g];
            }
        half8 ah[2];
#pragma unroll
        for (int p = 0; p < 12; ++p) {
            const int kt = p >> 1, hh = p & 1, buf = p & 1;
            const int pn = (p < 11) ? p + 1 : 0;  // p=11 prefetches next step's phase0
            stage(pn, buf ^ 1);
            // this wave's current-buf 2 loads are oldest; allow the 2 just issued
            asm volatile("s_waitcnt vmcnt(2)" ::: "memory");
            half8 bf0 = *((const half8*)(smB + buf * 16384 + (0 * 8 + w) * 1024) + l);
            half8 bf1 = *((const half8*)(smB + buf * 16384 + (1 * 8 + w) * 1024) + l);
            if (hh == 0) {
#pragma unroll
                for (int mt = 0; mt < 2; ++mt) {
                    int ped = mt * 16 + (l & 15);
                    int off = (ped * 384 + (kt * 32 + kgrp) * 2) ^ ((ped & 7) << 4);
                    ah[mt] = *(const half8*)(smA + off);
                }
            }
            const int g0 = hh * 2;
#pragma unroll
            for (int mt = 0; mt < 2; ++mt) {
                acc[mt][g0 + 0] = __builtin_amdgcn_mfma_f32_16x16x32_f16(ah[mt], bf0, acc[mt][g0 + 0], 0, 0, 0);
                acc[mt][g0 + 1] = __builtin_amdgcn_mfma_f32_16x16x32_f16(ah[mt], bf1, acc[mt][g0 + 1], 0, 0, 0);
            }
        }
        __syncthreads();  // B2: all A reads done before h overwrite

        // ---- S: nonlinearities + c/h update; lane owns (ped = mt*16+lrow+r, j = jlane)
#pragma unroll
        for (int mt = 0; mt < 2; ++mt) {
#pragma unroll
            for (int r = 0; r < 4; ++r) {
                float gi = acc[mt][0][r], gf = acc[mt][1][r];
                float gg = acc[mt][2][r], go = acc[mt][3][r];
                float i_ = sigm(gi), f_ = sigm(gf), g_ = tanhfast(gg), o_ = sigm(go);
                float cn = fmaf(f_, c[mt * 4 + r], i_ * g_);
                c[mt * 4 + r] = cn;
                float hn = o_ * tanhfast(cn);
                int ped = mt * 16 + lrow + r;
                int offb = (ped * 384 + 128 + jlane * 2) ^ ((ped & 7) << 4);
                *(_Float16*)(smA + offb) = (_Float16)hn;
            }
        }

        // ---- O: out = h @ Wout.T + bout (h f16 from LDS)
        if (step >= SEQ - 1) {
            __syncthreads();  // B3: h(step) visible
            if (l < 32) {
                const int oo = w & 1, jq = w >> 1;  // jq 0..3
                float s = 0.f;
#pragma unroll
                for (int t = 0; t < 4; ++t) {
                    int j = jq * 32 + t * 8;
                    int off = (l * 384 + 128 + j * 2) ^ ((l & 7) << 4);
                    half8 hh8 = *(const half8*)(smA + off);
                    const f32x4 w0 = *(const f32x4*)(Wout + oo * RNN + j);
                    const f32x4 w1 = *(const f32x4*)(Wout + oo * RNN + j + 4);
#pragma unroll
                    for (int i = 0; i < 4; ++i) {
                        s = fmaf((float)hh8[i], w0[i], s);
                        s = fmaf((float)hh8[i + 4], w1[i], s);
                    }
                }
                part[(l * 2 + oo) * 4 + jq] = s;
            }
            __syncthreads();  // B4
            if (tid < 64) {
                int pp = tid & 31, o2 = tid >> 5;
                const float* pr = &part[(pp * 2 + o2) * 4];
                float o = bout[o2] + ((pr[0] + pr[1]) + (pr[2] + pr[3]));
                outs[pp * 2 + o2] = o;
                if (step >= SEQ)
                    out[((size_t)(step - SEQ) * PEDS + (blockIdx.x * PB + pp)) * 2 + o2] = o;
            }
            __syncthreads();  // B5: outs visible for next E
        }
    }
}

extern "C" void kernel_launch(void* const* d_in, const int* in_sizes, int n_in,
                              void* d_out, int out_size, void* d_ws, size_t ws_size,
                              hipStream_t stream) {
    const float* obs  = (const float*)d_in[0];
    const float* Wemb = (const float*)d_in[1];
    const float* bemb = (const float*)d_in[2];
    const float* Wih  = (const float*)d_in[3];
    const float* bih  = (const float*)d_in[4];
    const float* Whh  = (const float*)d_in[5];
    const float* bhh  = (const float*)d_in[6];
    const float* Wout = (const float*)d_in[7];
    const float* bout = (const float*)d_in[8];

    _Float16* Bp  = (_Float16*)d_ws;                 // 98304 f16 = 192 KB
    float*    ewp = (float*)(Bp + 6 * 32 * 64 * 8);  // 64*4 f32 = 1 KB

    prep_kernel<<<(6 * 32 * 64 * 8 + 255) / 256, 256, 0, stream>>>(Wih, Whh, Wemb, bemb, Bp, ewp);
    lstm_kernel<<<PEDS / PB, NT, 0, stream>>>(obs, ewp, bih, bhh, Bp, Wout, bout, (float*)d_out);
}

// Round 15
// 228.713 us; speedup vs baseline: 3.2549x; 1.9821x over previous
//
#include <hip/hip_runtime.h>
#include <hip/hip_bf16.h>

#define SEQ   20
#define PRED  30
#define TSTEPS (SEQ + PRED)
#define PEDS  16384
#define EMB   64
#define RNN   128
#define PB    64
#define NT    512
#define L2E   1.44269504f

typedef _Float16 half8 __attribute__((ext_vector_type(8)));
typedef __attribute__((ext_vector_type(4))) float f32x4;

// inputs prescaled by log2e: sigma(x) = rcp(1 + 2^(-x'))
__device__ __forceinline__ float sigm2(float xp) {
    return __builtin_amdgcn_rcpf(1.f + __builtin_amdgcn_exp2f(-xp));
}
// tanh(x) with x' = x*log2e: 1 - 2/(2^(2x')+1); inf/0 paths give correct +-1
__device__ __forceinline__ float tanh2p(float xp) {
    float r = __builtin_amdgcn_rcpf(__builtin_amdgcn_exp2f(xp + xp) + 1.f);
    return fmaf(-2.f, r, 1.f);
}
__device__ __forceinline__ float tanh2u(float x) {  // unscaled input
    float r = __builtin_amdgcn_rcpf(__builtin_amdgcn_exp2f(x * (2.f * L2E)) + 1.f);
    return fmaf(-2.f, r, 1.f);
}

// B fragments (f16, PRESCALED by log2e): idx = ((kt*32 + nt)*64 + l)*8 + i
// nt = g*8 + jt ; row n = g*128 + jt*16 + (l&15) ; k = kt*32 + (l>>4)*8 + i
// ewp[ke][4] = {Wemb[ke][0], Wemb[ke][1], bemb[ke], 0}  (unscaled)
__global__ void prep_kernel(const float* __restrict__ Wih, const float* __restrict__ Whh,
                            const float* __restrict__ Wemb, const float* __restrict__ bemb,
                            _Float16* __restrict__ Bp, float* __restrict__ ewp) {
    int t = blockIdx.x * blockDim.x + threadIdx.x;
    if (t < 64) {
        ewp[t * 4 + 0] = Wemb[t * 2 + 0];
        ewp[t * 4 + 1] = Wemb[t * 2 + 1];
        ewp[t * 4 + 2] = bemb[t];
        ewp[t * 4 + 3] = 0.f;
    }
    if (t >= 6 * 32 * 64 * 8) return;
    int i  = t & 7;
    int l  = (t >> 3) & 63;
    int nt = (t >> 9) & 31;
    int kt = t >> 14;
    int n = (nt >> 3) * RNN + (nt & 7) * 16 + (l & 15);
    int k = kt * 32 + ((l >> 4) << 3) + i;
    float val = (k < EMB) ? Wih[n * EMB + k] : Whh[n * RNN + (k - EMB)];
    Bp[t] = (_Float16)(val * L2E);
}

// R9 base (8 waves, 1 block/CU, per-wave-private staging + vmcnt(4)) with:
// A double-buffered (no mid-step barrier), raw rcp/exp2 nonlinearities on
// log2e-prescaled gates, and step-invariant addresses hoisted to registers.
__global__ __launch_bounds__(NT, 2) void lstm_kernel(
    const float* __restrict__ obs,
    const float* __restrict__ ewp,
    const float* __restrict__ bih,  const float* __restrict__ bhh,
    const _Float16* __restrict__ Bp,
    const float* __restrict__ Wout, const float* __restrict__ bout,
    float* __restrict__ out)
{
    // A = [e(64) ; h(128)] f16, rows 384 B, XOR-swizzle ((row&7)<<4), dbuf.
    __shared__ __align__(16) char smA[2 * 24576];   // 48 KB
    __shared__ __align__(16) char smB[2 * 32768];   // 64 KB B dbuf
    __shared__ float smEW[64 * 4];                  // 1 KB embedding weights
    __shared__ float part[64 * 2 * 4];
    __shared__ float outs[64 * 2];

    const int tid = threadIdx.x;
    const int l   = tid & 63;
    const int w   = __builtin_amdgcn_readfirstlane(tid >> 6);  // wave 0..7 (= jt)
    const int pg  = blockIdx.x * PB + l;

    for (int r = tid; r < (2 * 24576) / 4; r += NT) ((int*)smA)[r] = 0;
    if (tid < 64) *(f32x4*)(smEW + tid * 4) = *(const f32x4*)(ewp + tid * 4);

    const int jlane = w * 16 + (l & 15);
    const int lrow  = (l >> 4) << 2;
    const int swz   = (l & 7) << 4;

    float bias[4];
#pragma unroll
    for (int g = 0; g < 4; ++g) {
        int n = g * RNN + jlane;
        bias[g] = (bih[n] + bhh[n]) * L2E;
    }

    // ---- step-invariant addresses ----
    int aBase[4];                       // G A-read: + kt*64, ^ swz
#pragma unroll
    for (int mt = 0; mt < 4; ++mt) {
        int ped = mt * 16 + (l & 15);
        aBase[mt] = ped * 384 + ((l >> 4) << 4);
    }
    int sAddr[4];                       // S h-store: + mt*6144 (imm fold)
#pragma unroll
    for (int r = 0; r < 4; ++r) {
        int ped = lrow + r;
        sAddr[r] = (ped * 384 + 128 + jlane * 2) ^ ((ped & 7) << 4);
    }
    const int eAddr = (l * 384 + w * 16) ^ swz;           // E e-store
    const int oBase = l * 384 + 128 + (w >> 1) * 64;      // O read (+t*16 ^ swz)
    const char* bb  = smB + l * 16;                        // B-read base
    const char* stageSrc = (const char*)Bp + l * 16 + w * 1024;

    // stage B slice kt -> buf: wave stages exactly the 4 fragments it reads
    auto stage = [&](int kt, int buf) {
#pragma unroll
        for (int g = 0; g < 4; ++g) {
            const void* src = stageSrc + kt * 32768 + g * 8192;
            __builtin_amdgcn_global_load_lds(
                (const __attribute__((address_space(1))) void*)src,
                (__attribute__((address_space(3))) void*)(smB + buf * 32768 + (g * 8 + w) * 1024),
                16, 0, 0);
        }
    };

    float c[16];
#pragma unroll
    for (int q = 0; q < 16; ++q) c[q] = 0.f;

    stage(0, 0);
    __syncthreads();

    const float* xptr = obs + (size_t)pg * 2;
    int curOff = 0;

    for (int step = 0; step < TSTEPS; ++step) {
        const int nxtOff = curOff ^ 24576;

        // ---- E: e = relu(x @ Wemb.T + bemb) -> A[cur] rows k=0..63
        {
            float x0, x1;
            if (step < SEQ) {
                x0 = xptr[0]; x1 = xptr[1];
                xptr += PEDS * 2;
            } else {
                x0 = outs[l * 2 + 0];
                x1 = outs[l * 2 + 1];
            }
            half8 vh;
#pragma unroll
            for (int q = 0; q < 8; ++q) {
                const f32x4 ew = *(const f32x4*)(smEW + (w * 8 + q) * 4);
                float v = fmaf(x0, ew[0], fmaf(x1, ew[1], ew[2]));
                vh[q] = (_Float16)fmaxf(v, 0.f);
            }
            *(half8*)(smA + curOff + eAddr) = vh;
        }
        __syncthreads();  // B1: e(step) + h(step-1) in A[cur] visible

        // ---- G: gates = A[64x192] @ B[192x512] + bias' ; f16 1-pass
        f32x4 acc[4][4];
#pragma unroll
        for (int mt = 0; mt < 4; ++mt)
#pragma unroll
            for (int g = 0; g < 4; ++g) {
                acc[mt][g][0] = bias[g]; acc[mt][g][1] = bias[g];
                acc[mt][g][2] = bias[g]; acc[mt][g][3] = bias[g];
            }
#pragma unroll
        for (int kt = 0; kt < 6; ++kt) {
            const int buf = kt & 1;
            const int ktn = (kt < 5) ? kt + 1 : 0;
            stage(ktn, buf ^ 1);
            asm volatile("s_waitcnt vmcnt(4)" ::: "memory");
            half8 bf[4];
#pragma unroll
            for (int g = 0; g < 4; ++g)
                bf[g] = *(const half8*)(bb + buf * 32768 + (g * 8 + w) * 1024);
#pragma unroll
            for (int mt = 0; mt < 4; ++mt) {
                half8 ah = *(const half8*)(smA + curOff + ((aBase[mt] + kt * 64) ^ swz));
#pragma unroll
                for (int g = 0; g < 4; ++g)
                    acc[mt][g] = __builtin_amdgcn_mfma_f32_16x16x32_f16(ah, bf[g], acc[mt][g], 0, 0, 0);
            }
        }
        // NO barrier: S writes h into A[nxt]; G of lagging waves reads A[cur].

        // ---- S: nonlinearities (prescaled) + c/h update; h -> A[nxt]
#pragma unroll
        for (int mt = 0; mt < 4; ++mt) {
#pragma unroll
            for (int r = 0; r < 4; ++r) {
                float gi = acc[mt][0][r], gf = acc[mt][1][r];
                float gg = acc[mt][2][r], go = acc[mt][3][r];
                float i_ = sigm2(gi), f_ = sigm2(gf), g_ = tanh2p(gg), o_ = sigm2(go);
                float cn = fmaf(f_, c[mt * 4 + r], i_ * g_);
                c[mt * 4 + r] = cn;
                float hn = o_ * tanh2u(cn);
                *(_Float16*)(smA + nxtOff + sAddr[r] + mt * 6144) = (_Float16)hn;
            }
        }

        // ---- O: out = h @ Wout.T + bout (h f16 from A[nxt])
        if (step >= SEQ - 1) {
            __syncthreads();  // B3: h(step) complete
            {
                const int oo = w & 1;
                float s = 0.f;
#pragma unroll
                for (int t = 0; t < 4; ++t) {
                    half8 hh8 = *(const half8*)(smA + nxtOff + ((oBase + t * 16) ^ swz));
                    const f32x4 w0 = *(const f32x4*)(Wout + oo * RNN + (w >> 1) * 32 + t * 8);
                    const f32x4 w1 = *(const f32x4*)(Wout + oo * RNN + (w >> 1) * 32 + t * 8 + 4);
#pragma unroll
                    for (int i = 0; i < 4; ++i) {
                        s = fmaf((float)hh8[i], w0[i], s);
                        s = fmaf((float)hh8[i + 4], w1[i], s);
                    }
                }
                part[(l * 2 + oo) * 4 + (w >> 1)] = s;
            }
            __syncthreads();  // B4
            if (tid < 128) {
                int pp = tid & 63, o2 = tid >> 6;
                const float* pr = &part[(pp * 2 + o2) * 4];
                float o = bout[o2] + ((pr[0] + pr[1]) + (pr[2] + pr[3]));
                outs[pp * 2 + o2] = o;
                if (step >= SEQ)
                    out[((size_t)(step - SEQ) * PEDS + (blockIdx.x * PB + pp)) * 2 + o2] = o;
            }
            __syncthreads();  // B5: outs visible for next E
        }
        curOff = nxtOff;
    }
}

extern "C" void kernel_launch(void* const* d_in, const int* in_sizes, int n_in,
                              void* d_out, int out_size, void* d_ws, size_t ws_size,
                              hipStream_t stream) {
    const float* obs  = (const float*)d_in[0];
    const float* Wemb = (const float*)d_in[1];
    const float* bemb = (const float*)d_in[2];
    const float* Wih  = (const float*)d_in[3];
    const float* bih  = (const float*)d_in[4];
    const float* Whh  = (const float*)d_in[5];
    const float* bhh  = (const float*)d_in[6];
    const float* Wout = (const float*)d_in[7];
    const float* bout = (const float*)d_in[8];

    _Float16* Bp  = (_Float16*)d_ws;                 // 98304 f16 = 192 KB
    float*    ewp = (float*)(Bp + 6 * 32 * 64 * 8);  // 64*4 f32 = 1 KB

    prep_kernel<<<(6 * 32 * 64 * 8 + 255) / 256, 256, 0, stream>>>(Wih, Whh, Wemb, bemb, Bp, ewp);
    lstm_kernel<<<PEDS / PB, NT, 0, stream>>>(obs, ewp, bih, bhh, Bp, Wout, bout, (float*)d_out);
}